// Round 11
// baseline (542.395 us; speedup 1.0000x reference)
//
#include <hip/hip_runtime.h>
#include <hip/hip_fp16.h>

#define N_NODES 50000
#define N_GRAPHS 500
#define E_SPARSE 800000
#define E_DENSE 3200000
#define IN_DIM 128
#define HID 128
#define OUT_D 64
#define N_LAYERS 3
#define NEG_SLOPE 0.2f

#define BUCKET_SHIFT 7                 // 128 nodes per bucket
#define BUCKET_N 128
#define NBUCK 391                      // ceil(50000/128)
#define NTD 1024                       // dense edge tiles (3125 edges/tile:
#define NTS 256                        //  small enough to counting-sort in LDS)
#define TS_D 3125                      // E_DENSE / NTD
#define TS_S 3125                      // E_SPARSE / NTS
#define MD (NBUCK * NTD)               // 400384
#define MATN (NBUCK * (NTD + NTS))     // 500480
#define NT 32                          // nodes per node_mm block
#define BMAX 10240                     // bucket_to_csr LDS staging bound
typedef unsigned int u32;
typedef unsigned short u16;
typedef _Float16 h16x8 __attribute__((ext_vector_type(8)));
typedef float f32x4 __attribute__((ext_vector_type(4)));  // for NT stores

// ---------------- CSR construction (both branches in one pass) -------------

__global__ __launch_bounds__(256) void tile_count_all(
    const int* __restrict__ dstD, const int* __restrict__ dstS,
    int* __restrict__ mat) {
    __shared__ int hc[NBUCK];
    int t = threadIdx.x;
    int tile = blockIdx.x;
    for (int i = t; i < NBUCK; i += 256) hc[i] = 0;
    __syncthreads();
    if (tile < NTD) {
        int beg = tile * TS_D, end = min(E_DENSE, beg + TS_D);
        for (int i = beg + t; i < end; i += 256)
            atomicAdd(&hc[dstD[i] >> BUCKET_SHIFT], 1);
        __syncthreads();
        for (int i = t; i < NBUCK; i += 256) mat[i * NTD + tile] = hc[i];
    } else {
        int st = tile - NTD;
        int beg = st * TS_S, end = min(E_SPARSE, beg + TS_S);
        for (int i = beg + t; i < end; i += 256)
            atomicAdd(&hc[dstS[i] >> BUCKET_SHIFT], 1);
        __syncthreads();
        for (int i = t; i < NBUCK; i += 256) mat[MD + i * NTS + st] = hc[i];
    }
}

// scan level-0: 512 threads, 4 elems/thread => 2048/block
__global__ void scan_lvl0(const int* __restrict__ cnt, int n,
                          int* __restrict__ out, int* __restrict__ bsum) {
    __shared__ int sm[512];
    int t = threadIdx.x;
    int base = blockIdx.x * 2048 + t * 4;
    int v0 = (base + 0 < n) ? cnt[base + 0] : 0;
    int v1 = (base + 1 < n) ? cnt[base + 1] : 0;
    int v2 = (base + 2 < n) ? cnt[base + 2] : 0;
    int v3 = (base + 3 < n) ? cnt[base + 3] : 0;
    int s = v0 + v1 + v2 + v3;
    sm[t] = s;
    __syncthreads();
    for (int off = 1; off < 512; off <<= 1) {
        int a = (t >= off) ? sm[t - off] : 0;
        __syncthreads();
        sm[t] += a;
        __syncthreads();
    }
    int excl = sm[t] - s;
    if (base + 0 < n) out[base + 0] = excl;
    if (base + 1 < n) out[base + 1] = excl + v0;
    if (base + 2 < n) out[base + 2] = excl + v0 + v1;
    if (base + 3 < n) out[base + 3] = excl + v0 + v1 + v2;
    if (t == 511) bsum[blockIdx.x] = sm[511];
}

// level-1: 256-thread LDS scan of block sums (nb <= 256)
__global__ void scan_lvl1(const int* __restrict__ bsum, int nb,
                          int* __restrict__ bsumx) {
    __shared__ int sm[256];
    int t = threadIdx.x;
    int v = (t < nb) ? bsum[t] : 0;
    sm[t] = v;
    __syncthreads();
    for (int off = 1; off < 256; off <<= 1) {
        int a = (t >= off) ? sm[t - off] : 0;
        __syncthreads();
        sm[t] += a;
        __syncthreads();
    }
    if (t < nb) bsumx[t] = sm[t] - v;
}

__global__ void scan_add(int* __restrict__ out, int n, const int* __restrict__ bsumx,
                         int Etot) {
    int i = blockIdx.x * blockDim.x + threadIdx.x;
    if (i < n) out[i] += bsumx[i >> 11];
    if (i == 0) out[n] = Etot;
}

// Counting-sort each tile in LDS, then write out bucket-sorted: coalesced
// writes (~1 request per 32B run instead of 1 per edge). [r9: verified —
// dropped tile_scatter out of the top-5, was 70-77us request-bound]
__global__ __launch_bounds__(256) void tile_scatter_all(
    const int* __restrict__ srcD, const int* __restrict__ dstD,
    const int* __restrict__ srcS, const int* __restrict__ dstS,
    const int* __restrict__ matx, u32* __restrict__ pairs) {
    __shared__ int hist[512];      // histogram -> inclusive scan
    __shared__ int curx[NBUCK];    // placement cursors
    __shared__ int gofs[NBUCK];    // global run base - local excl offset
    __shared__ u32 stg[TS_D];      // locally sorted packed entries
    __shared__ u16 bno[TS_D];      // bucket id per slot
    int t = threadIdx.x;
    int tile = blockIdx.x;
    const int* src;
    const int* dst;
    int beg, end, mbase, mstride;
    if (tile < NTD) {
        src = srcD; dst = dstD;
        beg = tile * TS_D; end = min(E_DENSE, beg + TS_D);
        mbase = tile; mstride = NTD;
    } else {
        int st = tile - NTD;
        src = srcS; dst = dstS;
        beg = st * TS_S; end = min(E_SPARSE, beg + TS_S);
        mbase = MD + st; mstride = NTS;
    }
    for (int i = t; i < 512; i += 256) hist[i] = 0;
    __syncthreads();
    for (int i = beg + t; i < end; i += 256)
        atomicAdd(&hist[dst[i] >> BUCKET_SHIFT], 1);
    __syncthreads();
    // inclusive scan over 512 entries, 2 per thread, read-barrier-write
    for (int off = 1; off < 512; off <<= 1) {
        int i0 = t, i1 = t + 256;
        int a0 = (i0 >= off) ? hist[i0 - off] : 0;
        int a1 = hist[i1 - off];               // i1 >= 256 >= off always
        __syncthreads();
        hist[i0] += a0; hist[i1] += a1;
        __syncthreads();
    }
    for (int b = t; b < NBUCK; b += 256) {
        int e = (b == 0) ? 0 : hist[b - 1];    // exclusive local offset
        curx[b] = e;
        gofs[b] = matx[b * mstride + mbase] - e;
    }
    __syncthreads();
    for (int i = beg + t; i < end; i += 256) {
        int d = dst[i];
        int b = d >> BUCKET_SHIFT;
        int p = atomicAdd(&curx[b], 1);
        stg[p] = (u32)src[i] | ((u32)(d & (BUCKET_N - 1)) << 16);
        bno[p] = (u16)b;
    }
    __syncthreads();
    int n = end - beg;
    for (int j = t; j < n; j += 256)
        pairs[gofs[bno[j]] + j] = stg[j];
}

// per-bucket local sort -> rowptr + u16 csrc. csrc staged in LDS, streamed
// out coalesced; guard falls back for oversized buckets.
__global__ __launch_bounds__(256) void bucket_to_csr_all(
    const u32* __restrict__ pairs, const int* __restrict__ matx,
    int* __restrict__ rowD, u16* __restrict__ csrcD,
    int* __restrict__ rowS, u16* __restrict__ csrcS) {
    int bid = blockIdx.x;
    int t = threadIdx.x;
    int b, beg, end, base;
    int* rowptr;
    u16* csrc;
    if (bid < NBUCK) {
        b = bid;
        beg = matx[b * NTD];
        end = matx[(b + 1) * NTD];     // b=390 -> matx[MD] = E_DENSE
        base = 0; rowptr = rowD; csrc = csrcD;
    } else {
        b = bid - NBUCK;
        beg = matx[MD + b * NTS];
        end = matx[MD + (b + 1) * NTS];  // last -> matx[MATN] = E_D+E_S
        base = E_DENSE; rowptr = rowS; csrc = csrcS;
    }
    __shared__ int lcnt[BUCKET_N];
    __shared__ int lofs[BUCKET_N];
    __shared__ u16 cstg[BMAX];         // 20KB csrc staging
    if (t < BUCKET_N) lcnt[t] = 0;
    __syncthreads();
    for (int k = beg + t; k < end; k += 256)
        atomicAdd(&lcnt[(pairs[k] >> 16) & (BUCKET_N - 1)], 1);
    __syncthreads();
    if (t < BUCKET_N) lofs[t] = lcnt[t];
    __syncthreads();
    for (int off = 1; off < BUCKET_N; off <<= 1) {
        int a = (t < BUCKET_N && t >= off) ? lofs[t - off] : 0;
        __syncthreads();
        if (t < BUCKET_N) lofs[t] += a;
        __syncthreads();
    }
    int node = (b << BUCKET_SHIFT) + t;
    int lbeg = beg - base;  // local CSR offset
    if (t < BUCKET_N) {
        int excl = lofs[t] - lcnt[t];
        if (node < N_NODES) rowptr[node] = lbeg + excl;
        lcnt[t] = excl;  // reuse as bucket-local cursor
    }
    if (b == NBUCK - 1 && t == 0)
        rowptr[N_NODES] = (base == 0) ? E_DENSE : E_SPARSE;
    __syncthreads();
    int bsize = end - beg;
    if (bsize <= BMAX) {
        for (int k = beg + t; k < end; k += 256) {
            u32 pr = pairs[k];
            int dl = (pr >> 16) & (BUCKET_N - 1);
            int pos = atomicAdd(&lcnt[dl], 1);
            cstg[pos] = (u16)(pr & 0xffffu);
        }
        __syncthreads();
        for (int j = t; j < bsize; j += 256)
            csrc[lbeg + j] = cstg[j];
    } else {  // statistically unreachable fallback (mean 8184, sigma ~90)
        for (int k = beg + t; k < end; k += 256) {
            u32 pr = pairs[k];
            int dl = (pr >> 16) & (BUCKET_N - 1);
            int pos = atomicAdd(&lcnt[dl], 1);
            csrc[lbeg + pos] = (u16)(pr & 0xffffu);
        }
    }
}

// ---------------- per-layer kernels ----------------------------------------

// 256 threads, 32 nodes/block. W (32KB) + X tile (16.9KB, padded) in LDS.
// h written in fp16 (unified 128B rows); s_src/s_dst raw fp32 scores.
__global__ __launch_bounds__(256) void node_mm2(
    const float* __restrict__ x, const float* __restrict__ W,
    const float* __restrict__ a_s, const float* __restrict__ a_d,
    __half* __restrict__ h, float* __restrict__ s_src, float* __restrict__ s_dst) {
    __shared__ float Wl[IN_DIM * OUT_D];        // [k][c], 32 KB
    __shared__ float4 Xl4[NT * 33];             // [n][33] float4 padded
    int t = threadIdx.x;
    int nbase = blockIdx.x * NT;

    const float4* W4 = (const float4*)W;
    float4* Wl4 = (float4*)Wl;
#pragma unroll
    for (int i = 0; i < 8; ++i) Wl4[t + 256 * i] = W4[t + 256 * i];

    int nrows = min(NT, N_NODES - nbase);
    const float4* X4 = (const float4*)(x + (size_t)nbase * IN_DIM);
    for (int i = t; i < nrows * 32; i += 256)
        Xl4[(i >> 5) * 33 + (i & 31)] = X4[i];
    __syncthreads();

    int wv = t >> 6, l = t & 63;
    int c4 = l & 15;
    int np = l >> 4;
    int n0 = wv * 8 + np * 2, n1 = n0 + 1;
    const float* Xl = (const float*)Xl4;
    const float4* Wr = (const float4*)Wl;

    float4 A0 = make_float4(0.f, 0.f, 0.f, 0.f);
    float4 A1 = make_float4(0.f, 0.f, 0.f, 0.f);
#pragma unroll 4
    for (int k = 0; k < IN_DIM; ++k) {
        float4 w4 = Wr[k * 16 + c4];
        float x0 = Xl[n0 * 132 + k];
        float x1 = Xl[n1 * 132 + k];
        A0.x += x0 * w4.x; A0.y += x0 * w4.y; A0.z += x0 * w4.z; A0.w += x0 * w4.w;
        A1.x += x1 * w4.x; A1.y += x1 * w4.y; A1.z += x1 * w4.z; A1.w += x1 * w4.w;
    }
    int gn0 = nbase + n0, gn1 = nbase + n1;
    if (gn0 < N_NODES) {
        __half2 v0 = __floats2half2_rn(A0.x, A0.y);
        __half2 v1 = __floats2half2_rn(A0.z, A0.w);
        float2 pk;
        pk.x = *(float*)&v0; pk.y = *(float*)&v1;
        ((float2*)(h + (size_t)gn0 * OUT_D))[c4] = pk;
    }
    if (gn1 < N_NODES) {
        __half2 v0 = __floats2half2_rn(A1.x, A1.y);
        __half2 v1 = __floats2half2_rn(A1.z, A1.w);
        float2 pk;
        pk.x = *(float*)&v0; pk.y = *(float*)&v1;
        ((float2*)(h + (size_t)gn1 * OUT_D))[c4] = pk;
    }

    float4 as4 = ((const float4*)a_s)[c4];
    float4 ad4 = ((const float4*)a_d)[c4];
    float ps0 = A0.x * as4.x + A0.y * as4.y + A0.z * as4.z + A0.w * as4.w;
    float pd0 = A0.x * ad4.x + A0.y * ad4.y + A0.z * ad4.z + A0.w * ad4.w;
    float ps1 = A1.x * as4.x + A1.y * as4.y + A1.z * as4.z + A1.w * as4.w;
    float pd1 = A1.x * ad4.x + A1.y * ad4.y + A1.z * ad4.z + A1.w * ad4.w;
#pragma unroll
    for (int off = 1; off < 16; off <<= 1) {
        ps0 += __shfl_xor(ps0, off); pd0 += __shfl_xor(pd0, off);
        ps1 += __shfl_xor(ps1, off); pd1 += __shfl_xor(pd1, off);
    }
    if (c4 == 0) {
        if (gn0 < N_NODES) { s_src[gn0] = ps0; s_dst[gn0] = pd0; }
        if (gn1 < N_NODES) { s_src[gn1] = ps1; s_dst[gn1] = pd1; }
    }
}

// acc += p * (8 fp16 channels). fmaf(fpext(h16), p, acc) — selects to
// v_fma_mix_f32 or cvt+fma; numerically identical either way.
__device__ __forceinline__ void accv(float4& a0, float4& a1, float p,
                                     const h16x8& r) {
    a0.x = fmaf((float)r[0], p, a0.x);
    a0.y = fmaf((float)r[1], p, a0.y);
    a0.z = fmaf((float)r[2], p, a0.z);
    a0.w = fmaf((float)r[3], p, a0.w);
    a1.x = fmaf((float)r[4], p, a1.x);
    a1.y = fmaf((float)r[5], p, a1.y);
    a1.z = fmaf((float)r[6], p, a1.z);
    a1.w = fmaf((float)r[7], p, a1.w);
}

// lrelu(e) = max(e, 0.2*e): bit-identical to predicated form.
__device__ __forceinline__ float lrelu(float e) {
    return fmaxf(e, NEG_SLOPE * e);
}

// NT store of a float4 via clang ext_vector (HIP float4 is a class type the
// builtin rejects; bit-identical layout).
__device__ __forceinline__ void nt_store4(float4 v, float4* p) {
    __builtin_nontemporal_store(*(f32x4*)&v, (f32x4*)p);
}

// Fused GAT aggregation (round-3 proven structure, ~72us/dispatch: the
// TCC-request-rate floor of 1 h-row line + 1 score line per edge).
// fuse_pool=0: NT-store xnext (don't evict the h table from L2).
// fuse_pool=1 (final layer): skip xnext entirely; dot the node's output with
// fw and atomicAdd into y[batch[node]] — removes the 25.6MB layer-3 store
// AND pool_final's 25.6MB re-read. (dot/sum commute; fp32 reorder only.)
__global__ __launch_bounds__(256, 8) void gat_aggr2(
    const int* __restrict__ rowS, const u16* __restrict__ csrcS,
    const int* __restrict__ rowD, const u16* __restrict__ csrcD,
    const float* __restrict__ s_src, const float* __restrict__ s_dst,
    const __half* __restrict__ h, const float* __restrict__ bias,
    float* __restrict__ xnext, int ngrid, int fuse_pool,
    const int* __restrict__ batch, const float* __restrict__ fw,
    float* __restrict__ y) {
    int bid = blockIdx.x;
    const int* rowptr;
    const u16* csrc;
    int col_off;
    if (bid < ngrid) { rowptr = rowS; csrc = csrcS; col_off = 0; }
    else { bid -= ngrid; rowptr = rowD; csrc = csrcD; col_off = OUT_D; }

    int node = bid * 4 + (threadIdx.x >> 6);
    if (node >= N_NODES) return;
    int lane = threadIdx.x & 63;
    int grp = lane >> 3;   // 0..7
    int sub = lane & 7;    // 0..7

    int beg = rowptr[node];
    int end = rowptr[node + 1];
    float sd = s_dst[node];

    const char* hb = (const char*)h;        // row = 128 bytes (64 halves)
    const char* sb = (const char*)s_src;
    u32 subo = (u32)sub * 16u;

    float4 a0 = make_float4(0.f, 0.f, 0.f, 0.f);  // channels sub*8 + 0..3
    float4 a1 = make_float4(0.f, 0.f, 0.f, 0.f);  // channels sub*8 + 4..7
    float z = 0.f;

    int k = beg + grp;
    for (; k + 24 < end; k += 32) {
        u32 s0 = csrc[k], s1 = csrc[k + 8], s2 = csrc[k + 16], s3 = csrc[k + 24];
        h16x8 r0 = *(const h16x8*)(hb + (s0 * 128u + subo));
        h16x8 r1 = *(const h16x8*)(hb + (s1 * 128u + subo));
        h16x8 r2 = *(const h16x8*)(hb + (s2 * 128u + subo));
        h16x8 r3 = *(const h16x8*)(hb + (s3 * 128u + subo));
        float e0 = *(const float*)(sb + s0 * 4u) + sd;
        float e1 = *(const float*)(sb + s1 * 4u) + sd;
        float e2 = *(const float*)(sb + s2 * 4u) + sd;
        float e3 = *(const float*)(sb + s3 * 4u) + sd;
        float p0 = __expf(lrelu(e0));
        float p1 = __expf(lrelu(e1));
        float p2 = __expf(lrelu(e2));
        float p3 = __expf(lrelu(e3));
        z += (p0 + p1) + (p2 + p3);
        accv(a0, a1, p0, r0);
        accv(a0, a1, p1, r1);
        accv(a0, a1, p2, r2);
        accv(a0, a1, p3, r3);
    }
    for (; k + 8 < end; k += 16) {
        u32 s0 = csrc[k], s1 = csrc[k + 8];
        h16x8 r0 = *(const h16x8*)(hb + (s0 * 128u + subo));
        h16x8 r1 = *(const h16x8*)(hb + (s1 * 128u + subo));
        float e0 = *(const float*)(sb + s0 * 4u) + sd;
        float e1 = *(const float*)(sb + s1 * 4u) + sd;
        float p0 = __expf(lrelu(e0));
        float p1 = __expf(lrelu(e1));
        z += p0 + p1;
        accv(a0, a1, p0, r0);
        accv(a0, a1, p1, r1);
    }
    if (k < end) {
        u32 s0 = csrc[k];
        h16x8 r0 = *(const h16x8*)(hb + (s0 * 128u + subo));
        float e0 = *(const float*)(sb + s0 * 4u) + sd;
        float p0 = __expf(lrelu(e0));
        z += p0;
        accv(a0, a1, p0, r0);
    }
    if (grp == 0) {  // self-loop exactly once
        h16x8 r0 = *(const h16x8*)(hb + ((u32)node * 128u + subo));
        float e0 = *(const float*)(sb + (u32)node * 4u) + sd;
        float p0 = __expf(lrelu(e0));
        z += p0;
        accv(a0, a1, p0, r0);
    }
#pragma unroll
    for (int off = 8; off <= 32; off <<= 1) {
        a0.x += __shfl_xor(a0.x, off); a0.y += __shfl_xor(a0.y, off);
        a0.z += __shfl_xor(a0.z, off); a0.w += __shfl_xor(a0.w, off);
        a1.x += __shfl_xor(a1.x, off); a1.y += __shfl_xor(a1.y, off);
        a1.z += __shfl_xor(a1.z, off); a1.w += __shfl_xor(a1.w, off);
        z += __shfl_xor(z, off);
    }
    if (grp == 0) {
        float inv = 1.f / z;
        const float4* b4 = (const float4*)bias;
        float4 b0 = b4[sub * 2], b1 = b4[sub * 2 + 1];
        float4 o0, o1;
        o0.x = a0.x * inv + b0.x; o0.y = a0.y * inv + b0.y;
        o0.z = a0.z * inv + b0.z; o0.w = a0.w * inv + b0.w;
        o1.x = a1.x * inv + b1.x; o1.y = a1.y * inv + b1.y;
        o1.z = a1.z * inv + b1.z; o1.w = a1.w * inv + b1.w;
        o0.x = fmaxf(o0.x, 0.f); o0.y = fmaxf(o0.y, 0.f);
        o0.z = fmaxf(o0.z, 0.f); o0.w = fmaxf(o0.w, 0.f);
        o1.x = fmaxf(o1.x, 0.f); o1.y = fmaxf(o1.y, 0.f);
        o1.z = fmaxf(o1.z, 0.f); o1.w = fmaxf(o1.w, 0.f);
        if (!fuse_pool) {
            float4* outp = (float4*)(xnext + (size_t)node * HID + col_off);
            nt_store4(o0, outp + sub * 2);
            nt_store4(o1, outp + sub * 2 + 1);
        } else {
            // dot this lane's 8 channels with fw, reduce over the 8 lanes
            // of the epilogue group, one atomic per node-branch.
            const float4* f4 = (const float4*)(fw + col_off);
            float4 f0 = f4[sub * 2], f1 = f4[sub * 2 + 1];
            float v = o0.x * f0.x + o0.y * f0.y + o0.z * f0.z + o0.w * f0.w
                    + o1.x * f1.x + o1.y * f1.y + o1.z * f1.z + o1.w * f1.w;
            v += __shfl_xor(v, 1);
            v += __shfl_xor(v, 2);
            v += __shfl_xor(v, 4);
            if (sub == 0) atomicAdd(&y[batch[node]], v);
        }
    }
}

// y[b] += fb[0]  (replaces pool_final; pooling fused into layer-3 gat)
__global__ void add_fb(float* __restrict__ y, const float* __restrict__ fb) {
    int i = blockIdx.x * blockDim.x + threadIdx.x;
    if (i < N_GRAPHS) y[i] += fb[0];
}

extern "C" void kernel_launch(void* const* d_in, const int* in_sizes, int n_in,
                              void* d_out, int out_size, void* d_ws, size_t ws_size,
                              hipStream_t stream) {
    const float* x_in    = (const float*)d_in[0];
    const int*   ei      = (const int*)d_in[1];
    const int*   di      = (const int*)d_in[2];
    const int*   batch   = (const int*)d_in[3];
    const float* lin_w   = (const float*)d_in[4];
    const float* att_src = (const float*)d_in[5];
    const float* att_dst = (const float*)d_in[6];
    const float* bias    = (const float*)d_in[7];
    const float* fw      = (const float*)d_in[8];
    const float* fb      = (const float*)d_in[9];
    float* y = (float*)d_out;

    char* wsb = (char*)d_ws;
    size_t off = 0;
    auto alloc_b = [&](size_t bytes) { void* p = (void*)(wsb + off);
                                       off += (bytes + 15) & ~(size_t)15; return p; };

    float* xbuf0 = (float*)alloc_b((size_t)N_NODES * HID * 4);
    float* xbuf1 = (float*)alloc_b((size_t)N_NODES * HID * 4);  // pairs during build
    __half* h    = (__half*)alloc_b((size_t)N_NODES * OUT_D * 2);
    float* s_src = (float*)alloc_b(N_NODES * 4);
    float* s_dst = (float*)alloc_b(N_NODES * 4);
    int* mat     = (int*)alloc_b((size_t)MATN * 4);
    int* matx    = (int*)alloc_b(((size_t)MATN + 1) * 4);
    int* bsum    = (int*)alloc_b(256 * 4);
    int* bsumx   = (int*)alloc_b(256 * 4);
    int* rowS    = (int*)alloc_b((N_NODES + 1) * 4);
    int* rowD    = (int*)alloc_b((N_NODES + 1) * 4);
    u16* csrcS   = (u16*)alloc_b((size_t)E_SPARSE * 2);
    u16* csrcD   = (u16*)alloc_b((size_t)E_DENSE * 2);
    u32* pairs   = (u32*)xbuf1;  // 16 MB needed <= 25.6 MB available

    const int* srcD = di;
    const int* dstD = di + E_DENSE;
    const int* srcS = ei;
    const int* dstS = ei + E_SPARSE;

    const int SCAN_BLKS = (MATN + 2047) / 2048;  // 245 <= 256

    // ---- combined CSR build (5 launches, shared across layers) ----
    tile_count_all<<<NTD + NTS, 256, 0, stream>>>(dstD, dstS, mat);
    scan_lvl0<<<SCAN_BLKS, 512, 0, stream>>>(mat, MATN, matx, bsum);
    scan_lvl1<<<1, 256, 0, stream>>>(bsum, SCAN_BLKS, bsumx);
    scan_add<<<(MATN + 256) / 256, 256, 0, stream>>>(matx, MATN, bsumx,
                                                     E_DENSE + E_SPARSE);
    tile_scatter_all<<<NTD + NTS, 256, 0, stream>>>(srcD, dstD, srcS, dstS,
                                                    matx, pairs);
    bucket_to_csr_all<<<2 * NBUCK, 256, 0, stream>>>(pairs, matx, rowD, csrcD,
                                                     rowS, csrcS);

    // layer 0 reads x_in directly; outputs ping-pong xbuf1 -> xbuf0; layer 3
    // pools directly into y (no xnext store).
    const float* cur = x_in;
    float* bufs[3] = {xbuf1, xbuf0, xbuf1};
    const int ngrid = (N_NODES + 3) / 4;
    const int mm_grid = (N_NODES + NT - 1) / NT;
    for (int l = 0; l < N_LAYERS; ++l) {
        node_mm2<<<mm_grid, 256, 0, stream>>>(cur, lin_w + (size_t)l * HID * OUT_D,
                                              att_src + l * OUT_D, att_dst + l * OUT_D,
                                              h, s_src, s_dst);
        float* xn = bufs[l];
        int fuse = (l == N_LAYERS - 1) ? 1 : 0;
        gat_aggr2<<<2 * ngrid, 256, 0, stream>>>(rowS, csrcS, rowD, csrcD,
                                                 s_src, s_dst, h,
                                                 bias + l * OUT_D, xn, ngrid,
                                                 fuse, batch, fw, y);
        cur = xn;
    }

    add_fb<<<2, 256, 0, stream>>>(y, fb);
}

// Round 12
// 431.587 us; speedup vs baseline: 1.2567x; 1.2567x over previous
//
#include <hip/hip_runtime.h>
#include <hip/hip_fp16.h>

#define N_NODES 50000
#define N_GRAPHS 500
#define E_SPARSE 800000
#define E_DENSE 3200000
#define IN_DIM 128
#define HID 128
#define OUT_D 64
#define N_LAYERS 3
#define NEG_SLOPE 0.2f

#define BUCKET_SHIFT 7                 // 128 nodes per bucket
#define BUCKET_N 128
#define NBUCK 391                      // ceil(50000/128)
#define NTD 1024                       // dense edge tiles (3125 edges/tile:
#define NTS 256                        //  small enough to counting-sort in LDS)
#define TS_D 3125                      // E_DENSE / NTD
#define TS_S 3125                      // E_SPARSE / NTS
#define MD (NBUCK * NTD)               // 400384
#define MATN (NBUCK * (NTD + NTS))     // 500480
#define NT 32                          // nodes per node_mm block
#define BMAX 10240                     // bucket_to_csr LDS staging bound
typedef unsigned int u32;
typedef unsigned short u16;
typedef _Float16 h16x8 __attribute__((ext_vector_type(8)));

// ---------------- CSR construction (both branches in one pass) -------------

__global__ __launch_bounds__(256) void tile_count_all(
    const int* __restrict__ dstD, const int* __restrict__ dstS,
    int* __restrict__ mat) {
    __shared__ int hc[NBUCK];
    int t = threadIdx.x;
    int tile = blockIdx.x;
    for (int i = t; i < NBUCK; i += 256) hc[i] = 0;
    __syncthreads();
    if (tile < NTD) {
        int beg = tile * TS_D, end = min(E_DENSE, beg + TS_D);
        for (int i = beg + t; i < end; i += 256)
            atomicAdd(&hc[dstD[i] >> BUCKET_SHIFT], 1);
        __syncthreads();
        for (int i = t; i < NBUCK; i += 256) mat[i * NTD + tile] = hc[i];
    } else {
        int st = tile - NTD;
        int beg = st * TS_S, end = min(E_SPARSE, beg + TS_S);
        for (int i = beg + t; i < end; i += 256)
            atomicAdd(&hc[dstS[i] >> BUCKET_SHIFT], 1);
        __syncthreads();
        for (int i = t; i < NBUCK; i += 256) mat[MD + i * NTS + st] = hc[i];
    }
}

// scan level-0: 512 threads, 4 elems/thread => 2048/block
__global__ void scan_lvl0(const int* __restrict__ cnt, int n,
                          int* __restrict__ out, int* __restrict__ bsum) {
    __shared__ int sm[512];
    int t = threadIdx.x;
    int base = blockIdx.x * 2048 + t * 4;
    int v0 = (base + 0 < n) ? cnt[base + 0] : 0;
    int v1 = (base + 1 < n) ? cnt[base + 1] : 0;
    int v2 = (base + 2 < n) ? cnt[base + 2] : 0;
    int v3 = (base + 3 < n) ? cnt[base + 3] : 0;
    int s = v0 + v1 + v2 + v3;
    sm[t] = s;
    __syncthreads();
    for (int off = 1; off < 512; off <<= 1) {
        int a = (t >= off) ? sm[t - off] : 0;
        __syncthreads();
        sm[t] += a;
        __syncthreads();
    }
    int excl = sm[t] - s;
    if (base + 0 < n) out[base + 0] = excl;
    if (base + 1 < n) out[base + 1] = excl + v0;
    if (base + 2 < n) out[base + 2] = excl + v0 + v1;
    if (base + 3 < n) out[base + 3] = excl + v0 + v1 + v2;
    if (t == 511) bsum[blockIdx.x] = sm[511];
}

// level-1: 256-thread LDS scan of block sums (nb <= 256)
__global__ void scan_lvl1(const int* __restrict__ bsum, int nb,
                          int* __restrict__ bsumx) {
    __shared__ int sm[256];
    int t = threadIdx.x;
    int v = (t < nb) ? bsum[t] : 0;
    sm[t] = v;
    __syncthreads();
    for (int off = 1; off < 256; off <<= 1) {
        int a = (t >= off) ? sm[t - off] : 0;
        __syncthreads();
        sm[t] += a;
        __syncthreads();
    }
    if (t < nb) bsumx[t] = sm[t] - v;
}

__global__ void scan_add(int* __restrict__ out, int n, const int* __restrict__ bsumx,
                         int Etot) {
    int i = blockIdx.x * blockDim.x + threadIdx.x;
    if (i < n) out[i] += bsumx[i >> 11];
    if (i == 0) out[n] = Etot;
}

// Counting-sort each tile in LDS, then write out bucket-sorted: coalesced
// writes (~1 request per 32B run instead of 1 per edge). [r9: verified]
__global__ __launch_bounds__(256) void tile_scatter_all(
    const int* __restrict__ srcD, const int* __restrict__ dstD,
    const int* __restrict__ srcS, const int* __restrict__ dstS,
    const int* __restrict__ matx, u32* __restrict__ pairs) {
    __shared__ int hist[512];      // histogram -> inclusive scan
    __shared__ int curx[NBUCK];    // placement cursors
    __shared__ int gofs[NBUCK];    // global run base - local excl offset
    __shared__ u32 stg[TS_D];      // locally sorted packed entries
    __shared__ u16 bno[TS_D];      // bucket id per slot
    int t = threadIdx.x;
    int tile = blockIdx.x;
    const int* src;
    const int* dst;
    int beg, end, mbase, mstride;
    if (tile < NTD) {
        src = srcD; dst = dstD;
        beg = tile * TS_D; end = min(E_DENSE, beg + TS_D);
        mbase = tile; mstride = NTD;
    } else {
        int st = tile - NTD;
        src = srcS; dst = dstS;
        beg = st * TS_S; end = min(E_SPARSE, beg + TS_S);
        mbase = MD + st; mstride = NTS;
    }
    for (int i = t; i < 512; i += 256) hist[i] = 0;
    __syncthreads();
    for (int i = beg + t; i < end; i += 256)
        atomicAdd(&hist[dst[i] >> BUCKET_SHIFT], 1);
    __syncthreads();
    // inclusive scan over 512 entries, 2 per thread, read-barrier-write
    for (int off = 1; off < 512; off <<= 1) {
        int i0 = t, i1 = t + 256;
        int a0 = (i0 >= off) ? hist[i0 - off] : 0;
        int a1 = hist[i1 - off];               // i1 >= 256 >= off always
        __syncthreads();
        hist[i0] += a0; hist[i1] += a1;
        __syncthreads();
    }
    for (int b = t; b < NBUCK; b += 256) {
        int e = (b == 0) ? 0 : hist[b - 1];    // exclusive local offset
        curx[b] = e;
        gofs[b] = matx[b * mstride + mbase] - e;
    }
    __syncthreads();
    for (int i = beg + t; i < end; i += 256) {
        int d = dst[i];
        int b = d >> BUCKET_SHIFT;
        int p = atomicAdd(&curx[b], 1);
        stg[p] = (u32)src[i] | ((u32)(d & (BUCKET_N - 1)) << 16);
        bno[p] = (u16)b;
    }
    __syncthreads();
    int n = end - beg;
    for (int j = t; j < n; j += 256)
        pairs[gofs[bno[j]] + j] = stg[j];
}

// per-bucket local sort -> rowptr + u16 csrc. csrc staged in LDS, streamed
// out coalesced; guard falls back for oversized buckets.
__global__ __launch_bounds__(256) void bucket_to_csr_all(
    const u32* __restrict__ pairs, const int* __restrict__ matx,
    int* __restrict__ rowD, u16* __restrict__ csrcD,
    int* __restrict__ rowS, u16* __restrict__ csrcS) {
    int bid = blockIdx.x;
    int t = threadIdx.x;
    int b, beg, end, base;
    int* rowptr;
    u16* csrc;
    if (bid < NBUCK) {
        b = bid;
        beg = matx[b * NTD];
        end = matx[(b + 1) * NTD];     // b=390 -> matx[MD] = E_DENSE
        base = 0; rowptr = rowD; csrc = csrcD;
    } else {
        b = bid - NBUCK;
        beg = matx[MD + b * NTS];
        end = matx[MD + (b + 1) * NTS];  // last -> matx[MATN] = E_D+E_S
        base = E_DENSE; rowptr = rowS; csrc = csrcS;
    }
    __shared__ int lcnt[BUCKET_N];
    __shared__ int lofs[BUCKET_N];
    __shared__ u16 cstg[BMAX];         // 20KB csrc staging
    if (t < BUCKET_N) lcnt[t] = 0;
    __syncthreads();
    for (int k = beg + t; k < end; k += 256)
        atomicAdd(&lcnt[(pairs[k] >> 16) & (BUCKET_N - 1)], 1);
    __syncthreads();
    if (t < BUCKET_N) lofs[t] = lcnt[t];
    __syncthreads();
    for (int off = 1; off < BUCKET_N; off <<= 1) {
        int a = (t < BUCKET_N && t >= off) ? lofs[t - off] : 0;
        __syncthreads();
        if (t < BUCKET_N) lofs[t] += a;
        __syncthreads();
    }
    int node = (b << BUCKET_SHIFT) + t;
    int lbeg = beg - base;  // local CSR offset
    if (t < BUCKET_N) {
        int excl = lofs[t] - lcnt[t];
        if (node < N_NODES) rowptr[node] = lbeg + excl;
        lcnt[t] = excl;  // reuse as bucket-local cursor
    }
    if (b == NBUCK - 1 && t == 0)
        rowptr[N_NODES] = (base == 0) ? E_DENSE : E_SPARSE;
    __syncthreads();
    int bsize = end - beg;
    if (bsize <= BMAX) {
        for (int k = beg + t; k < end; k += 256) {
            u32 pr = pairs[k];
            int dl = (pr >> 16) & (BUCKET_N - 1);
            int pos = atomicAdd(&lcnt[dl], 1);
            cstg[pos] = (u16)(pr & 0xffffu);
        }
        __syncthreads();
        for (int j = t; j < bsize; j += 256)
            csrc[lbeg + j] = cstg[j];
    } else {  // statistically unreachable fallback (mean 8184, sigma ~90)
        for (int k = beg + t; k < end; k += 256) {
            u32 pr = pairs[k];
            int dl = (pr >> 16) & (BUCKET_N - 1);
            int pos = atomicAdd(&lcnt[dl], 1);
            csrc[lbeg + pos] = (u16)(pr & 0xffffu);
        }
    }
}

// ---------------- per-layer kernels ----------------------------------------

// 256 threads, 32 nodes/block. W (32KB) + X tile (16.9KB, padded) in LDS.
// h written in fp16 (unified 128B rows); s_src/s_dst raw fp32 scores.
__global__ __launch_bounds__(256) void node_mm2(
    const float* __restrict__ x, const float* __restrict__ W,
    const float* __restrict__ a_s, const float* __restrict__ a_d,
    __half* __restrict__ h, float* __restrict__ s_src, float* __restrict__ s_dst) {
    __shared__ float Wl[IN_DIM * OUT_D];        // [k][c], 32 KB
    __shared__ float4 Xl4[NT * 33];             // [n][33] float4 padded
    int t = threadIdx.x;
    int nbase = blockIdx.x * NT;

    const float4* W4 = (const float4*)W;
    float4* Wl4 = (float4*)Wl;
#pragma unroll
    for (int i = 0; i < 8; ++i) Wl4[t + 256 * i] = W4[t + 256 * i];

    int nrows = min(NT, N_NODES - nbase);
    const float4* X4 = (const float4*)(x + (size_t)nbase * IN_DIM);
    for (int i = t; i < nrows * 32; i += 256)
        Xl4[(i >> 5) * 33 + (i & 31)] = X4[i];
    __syncthreads();

    int wv = t >> 6, l = t & 63;
    int c4 = l & 15;
    int np = l >> 4;
    int n0 = wv * 8 + np * 2, n1 = n0 + 1;
    const float* Xl = (const float*)Xl4;
    const float4* Wr = (const float4*)Wl;

    float4 A0 = make_float4(0.f, 0.f, 0.f, 0.f);
    float4 A1 = make_float4(0.f, 0.f, 0.f, 0.f);
#pragma unroll 4
    for (int k = 0; k < IN_DIM; ++k) {
        float4 w4 = Wr[k * 16 + c4];
        float x0 = Xl[n0 * 132 + k];
        float x1 = Xl[n1 * 132 + k];
        A0.x += x0 * w4.x; A0.y += x0 * w4.y; A0.z += x0 * w4.z; A0.w += x0 * w4.w;
        A1.x += x1 * w4.x; A1.y += x1 * w4.y; A1.z += x1 * w4.z; A1.w += x1 * w4.w;
    }
    int gn0 = nbase + n0, gn1 = nbase + n1;
    if (gn0 < N_NODES) {
        __half2 v0 = __floats2half2_rn(A0.x, A0.y);
        __half2 v1 = __floats2half2_rn(A0.z, A0.w);
        float2 pk;
        pk.x = *(float*)&v0; pk.y = *(float*)&v1;
        ((float2*)(h + (size_t)gn0 * OUT_D))[c4] = pk;
    }
    if (gn1 < N_NODES) {
        __half2 v0 = __floats2half2_rn(A1.x, A1.y);
        __half2 v1 = __floats2half2_rn(A1.z, A1.w);
        float2 pk;
        pk.x = *(float*)&v0; pk.y = *(float*)&v1;
        ((float2*)(h + (size_t)gn1 * OUT_D))[c4] = pk;
    }

    float4 as4 = ((const float4*)a_s)[c4];
    float4 ad4 = ((const float4*)a_d)[c4];
    float ps0 = A0.x * as4.x + A0.y * as4.y + A0.z * as4.z + A0.w * as4.w;
    float pd0 = A0.x * ad4.x + A0.y * ad4.y + A0.z * ad4.z + A0.w * ad4.w;
    float ps1 = A1.x * as4.x + A1.y * as4.y + A1.z * as4.z + A1.w * as4.w;
    float pd1 = A1.x * ad4.x + A1.y * ad4.y + A1.z * ad4.z + A1.w * ad4.w;
#pragma unroll
    for (int off = 1; off < 16; off <<= 1) {
        ps0 += __shfl_xor(ps0, off); pd0 += __shfl_xor(pd0, off);
        ps1 += __shfl_xor(ps1, off); pd1 += __shfl_xor(pd1, off);
    }
    if (c4 == 0) {
        if (gn0 < N_NODES) { s_src[gn0] = ps0; s_dst[gn0] = pd0; }
        if (gn1 < N_NODES) { s_src[gn1] = ps1; s_dst[gn1] = pd1; }
    }
}

// acc += p * (8 fp16 channels). fmaf(fpext(h16), p, acc) — selects to
// v_fma_mix_f32 or cvt+fma; numerically identical either way.
__device__ __forceinline__ void accv(float4& a0, float4& a1, float p,
                                     const h16x8& r) {
    a0.x = fmaf((float)r[0], p, a0.x);
    a0.y = fmaf((float)r[1], p, a0.y);
    a0.z = fmaf((float)r[2], p, a0.z);
    a0.w = fmaf((float)r[3], p, a0.w);
    a1.x = fmaf((float)r[4], p, a1.x);
    a1.y = fmaf((float)r[5], p, a1.y);
    a1.z = fmaf((float)r[6], p, a1.z);
    a1.w = fmaf((float)r[7], p, a1.w);
}

// lrelu(e) = max(e, 0.2*e): bit-identical to predicated form.
__device__ __forceinline__ float lrelu(float e) {
    return fmaxf(e, NEG_SLOPE * e);
}

// Fused GAT aggregation (round-3 proven structure, ~72us/dispatch: the
// TCC-request-rate floor of 1 h-row line + 1 score line per edge).
// fuse_pool=1 (final layer): skip the 25.6MB xnext store; write the node's
// fw-dot to a PER-NODE scratch slot (plain store, distinct address — r11's
// atomicAdd-to-y[graph] serialized on sorted batch, 180us). pn layout:
// [0,N) = branch-S partial, [N,2N) = branch-D partial.
__global__ __launch_bounds__(256, 8) void gat_aggr2(
    const int* __restrict__ rowS, const u16* __restrict__ csrcS,
    const int* __restrict__ rowD, const u16* __restrict__ csrcD,
    const float* __restrict__ s_src, const float* __restrict__ s_dst,
    const __half* __restrict__ h, const float* __restrict__ bias,
    float* __restrict__ xnext, int ngrid, int fuse_pool,
    const float* __restrict__ fw, float* __restrict__ pn) {
    int bid = blockIdx.x;
    const int* rowptr;
    const u16* csrc;
    int col_off;
    if (bid < ngrid) { rowptr = rowS; csrc = csrcS; col_off = 0; }
    else { bid -= ngrid; rowptr = rowD; csrc = csrcD; col_off = OUT_D; }

    int node = bid * 4 + (threadIdx.x >> 6);
    if (node >= N_NODES) return;
    int lane = threadIdx.x & 63;
    int grp = lane >> 3;   // 0..7
    int sub = lane & 7;    // 0..7

    int beg = rowptr[node];
    int end = rowptr[node + 1];
    float sd = s_dst[node];

    const char* hb = (const char*)h;        // row = 128 bytes (64 halves)
    const char* sb = (const char*)s_src;
    u32 subo = (u32)sub * 16u;

    float4 a0 = make_float4(0.f, 0.f, 0.f, 0.f);  // channels sub*8 + 0..3
    float4 a1 = make_float4(0.f, 0.f, 0.f, 0.f);  // channels sub*8 + 4..7
    float z = 0.f;

    int k = beg + grp;
    for (; k + 24 < end; k += 32) {
        u32 s0 = csrc[k], s1 = csrc[k + 8], s2 = csrc[k + 16], s3 = csrc[k + 24];
        h16x8 r0 = *(const h16x8*)(hb + (s0 * 128u + subo));
        h16x8 r1 = *(const h16x8*)(hb + (s1 * 128u + subo));
        h16x8 r2 = *(const h16x8*)(hb + (s2 * 128u + subo));
        h16x8 r3 = *(const h16x8*)(hb + (s3 * 128u + subo));
        float e0 = *(const float*)(sb + s0 * 4u) + sd;
        float e1 = *(const float*)(sb + s1 * 4u) + sd;
        float e2 = *(const float*)(sb + s2 * 4u) + sd;
        float e3 = *(const float*)(sb + s3 * 4u) + sd;
        float p0 = __expf(lrelu(e0));
        float p1 = __expf(lrelu(e1));
        float p2 = __expf(lrelu(e2));
        float p3 = __expf(lrelu(e3));
        z += (p0 + p1) + (p2 + p3);
        accv(a0, a1, p0, r0);
        accv(a0, a1, p1, r1);
        accv(a0, a1, p2, r2);
        accv(a0, a1, p3, r3);
    }
    for (; k + 8 < end; k += 16) {
        u32 s0 = csrc[k], s1 = csrc[k + 8];
        h16x8 r0 = *(const h16x8*)(hb + (s0 * 128u + subo));
        h16x8 r1 = *(const h16x8*)(hb + (s1 * 128u + subo));
        float e0 = *(const float*)(sb + s0 * 4u) + sd;
        float e1 = *(const float*)(sb + s1 * 4u) + sd;
        float p0 = __expf(lrelu(e0));
        float p1 = __expf(lrelu(e1));
        z += p0 + p1;
        accv(a0, a1, p0, r0);
        accv(a0, a1, p1, r1);
    }
    if (k < end) {
        u32 s0 = csrc[k];
        h16x8 r0 = *(const h16x8*)(hb + (s0 * 128u + subo));
        float e0 = *(const float*)(sb + s0 * 4u) + sd;
        float p0 = __expf(lrelu(e0));
        z += p0;
        accv(a0, a1, p0, r0);
    }
    if (grp == 0) {  // self-loop exactly once
        h16x8 r0 = *(const h16x8*)(hb + ((u32)node * 128u + subo));
        float e0 = *(const float*)(sb + (u32)node * 4u) + sd;
        float p0 = __expf(lrelu(e0));
        z += p0;
        accv(a0, a1, p0, r0);
    }
#pragma unroll
    for (int off = 8; off <= 32; off <<= 1) {
        a0.x += __shfl_xor(a0.x, off); a0.y += __shfl_xor(a0.y, off);
        a0.z += __shfl_xor(a0.z, off); a0.w += __shfl_xor(a0.w, off);
        a1.x += __shfl_xor(a1.x, off); a1.y += __shfl_xor(a1.y, off);
        a1.z += __shfl_xor(a1.z, off); a1.w += __shfl_xor(a1.w, off);
        z += __shfl_xor(z, off);
    }
    if (grp == 0) {
        float inv = 1.f / z;
        const float4* b4 = (const float4*)bias;
        float4 b0 = b4[sub * 2], b1 = b4[sub * 2 + 1];
        float4 o0, o1;
        o0.x = a0.x * inv + b0.x; o0.y = a0.y * inv + b0.y;
        o0.z = a0.z * inv + b0.z; o0.w = a0.w * inv + b0.w;
        o1.x = a1.x * inv + b1.x; o1.y = a1.y * inv + b1.y;
        o1.z = a1.z * inv + b1.z; o1.w = a1.w * inv + b1.w;
        o0.x = fmaxf(o0.x, 0.f); o0.y = fmaxf(o0.y, 0.f);
        o0.z = fmaxf(o0.z, 0.f); o0.w = fmaxf(o0.w, 0.f);
        o1.x = fmaxf(o1.x, 0.f); o1.y = fmaxf(o1.y, 0.f);
        o1.z = fmaxf(o1.z, 0.f); o1.w = fmaxf(o1.w, 0.f);
        if (!fuse_pool) {
            float4* outp = (float4*)(xnext + (size_t)node * HID + col_off);
            outp[sub * 2] = o0;
            outp[sub * 2 + 1] = o1;
        } else {
            // dot this lane's 8 channels with fw, reduce over the 8 epilogue
            // lanes, PLAIN store to the per-node slot (no contention).
            const float4* f4 = (const float4*)(fw + col_off);
            float4 f0 = f4[sub * 2], f1 = f4[sub * 2 + 1];
            float v = o0.x * f0.x + o0.y * f0.y + o0.z * f0.z + o0.w * f0.w
                    + o1.x * f1.x + o1.y * f1.y + o1.z * f1.z + o1.w * f1.w;
            v += __shfl_xor(v, 1);
            v += __shfl_xor(v, 2);
            v += __shfl_xor(v, 4);
            if (sub == 0) pn[(col_off ? N_NODES : 0) + node] = v;
        }
    }
}

// Final pool over per-node dot products: one block per graph (batch sorted),
// reads 400KB total (vs pool_final's 25.6MB re-read of xnext).
__global__ __launch_bounds__(128) void pool_small(
    const float* __restrict__ pn, const int* __restrict__ batch,
    const float* __restrict__ fb, float* __restrict__ y) {
    int b = blockIdx.x;
    int t = threadIdx.x;  // 0..127
    __shared__ int sbeg, send;
    if (t == 0) {
        int lo = 0, hi = N_NODES;
        while (lo < hi) { int mid = (lo + hi) >> 1; if (batch[mid] < b) lo = mid + 1; else hi = mid; }
        sbeg = lo;
        hi = N_NODES;
        while (lo < hi) { int mid = (lo + hi) >> 1; if (batch[mid] < b + 1) lo = mid + 1; else hi = mid; }
        send = lo;
    }
    __syncthreads();
    float acc = 0.f;
    for (int n = sbeg + t; n < send; n += 128)
        acc += pn[n] + pn[N_NODES + n];
    __shared__ float sm[128];
    sm[t] = acc;
    __syncthreads();
    for (int off = 64; off > 0; off >>= 1) {
        if (t < off) sm[t] += sm[t + off];
        __syncthreads();
    }
    if (t == 0) y[b] = sm[0] + fb[0];
}

extern "C" void kernel_launch(void* const* d_in, const int* in_sizes, int n_in,
                              void* d_out, int out_size, void* d_ws, size_t ws_size,
                              hipStream_t stream) {
    const float* x_in    = (const float*)d_in[0];
    const int*   ei      = (const int*)d_in[1];
    const int*   di      = (const int*)d_in[2];
    const int*   batch   = (const int*)d_in[3];
    const float* lin_w   = (const float*)d_in[4];
    const float* att_src = (const float*)d_in[5];
    const float* att_dst = (const float*)d_in[6];
    const float* bias    = (const float*)d_in[7];
    const float* fw      = (const float*)d_in[8];
    const float* fb      = (const float*)d_in[9];
    float* y = (float*)d_out;

    char* wsb = (char*)d_ws;
    size_t off = 0;
    auto alloc_b = [&](size_t bytes) { void* p = (void*)(wsb + off);
                                       off += (bytes + 15) & ~(size_t)15; return p; };

    float* xbuf0 = (float*)alloc_b((size_t)N_NODES * HID * 4);
    float* xbuf1 = (float*)alloc_b((size_t)N_NODES * HID * 4);  // pairs during build
    __half* h    = (__half*)alloc_b((size_t)N_NODES * OUT_D * 2);
    float* s_src = (float*)alloc_b(N_NODES * 4);
    float* s_dst = (float*)alloc_b(N_NODES * 4);
    float* pn    = (float*)alloc_b((size_t)2 * N_NODES * 4);  // per-node dots
    int* mat     = (int*)alloc_b((size_t)MATN * 4);
    int* matx    = (int*)alloc_b(((size_t)MATN + 1) * 4);
    int* bsum    = (int*)alloc_b(256 * 4);
    int* bsumx   = (int*)alloc_b(256 * 4);
    int* rowS    = (int*)alloc_b((N_NODES + 1) * 4);
    int* rowD    = (int*)alloc_b((N_NODES + 1) * 4);
    u16* csrcS   = (u16*)alloc_b((size_t)E_SPARSE * 2);
    u16* csrcD   = (u16*)alloc_b((size_t)E_DENSE * 2);
    u32* pairs   = (u32*)xbuf1;  // 16 MB needed <= 25.6 MB available

    const int* srcD = di;
    const int* dstD = di + E_DENSE;
    const int* srcS = ei;
    const int* dstS = ei + E_SPARSE;

    const int SCAN_BLKS = (MATN + 2047) / 2048;  // 245 <= 256

    // ---- combined CSR build (5 launches, shared across layers) ----
    tile_count_all<<<NTD + NTS, 256, 0, stream>>>(dstD, dstS, mat);
    scan_lvl0<<<SCAN_BLKS, 512, 0, stream>>>(mat, MATN, matx, bsum);
    scan_lvl1<<<1, 256, 0, stream>>>(bsum, SCAN_BLKS, bsumx);
    scan_add<<<(MATN + 256) / 256, 256, 0, stream>>>(matx, MATN, bsumx,
                                                     E_DENSE + E_SPARSE);
    tile_scatter_all<<<NTD + NTS, 256, 0, stream>>>(srcD, dstD, srcS, dstS,
                                                    matx, pairs);
    bucket_to_csr_all<<<2 * NBUCK, 256, 0, stream>>>(pairs, matx, rowD, csrcD,
                                                     rowS, csrcS);

    // layer 0 reads x_in directly; outputs ping-pong xbuf1 -> xbuf0; layer 3
    // writes per-node dot products (no xnext store).
    const float* cur = x_in;
    float* bufs[3] = {xbuf1, xbuf0, xbuf1};
    const int ngrid = (N_NODES + 3) / 4;
    const int mm_grid = (N_NODES + NT - 1) / NT;
    for (int l = 0; l < N_LAYERS; ++l) {
        node_mm2<<<mm_grid, 256, 0, stream>>>(cur, lin_w + (size_t)l * HID * OUT_D,
                                              att_src + l * OUT_D, att_dst + l * OUT_D,
                                              h, s_src, s_dst);
        float* xn = bufs[l];
        int fuse = (l == N_LAYERS - 1) ? 1 : 0;
        gat_aggr2<<<2 * ngrid, 256, 0, stream>>>(rowS, csrcS, rowD, csrcD,
                                                 s_src, s_dst, h,
                                                 bias + l * OUT_D, xn, ngrid,
                                                 fuse, fw, pn);
        cur = xn;
    }

    pool_small<<<N_GRAPHS, 128, 0, stream>>>(pn, batch, fb, y);
}